// Round 1
// baseline (20491.875 us; speedup 1.0000x reference)
//
#include <hip/hip_runtime.h>
#include <hip/hip_fp16.h>
#include <stdint.h>

// DMSRNN: r_{t+1} = 0.8*r_t + 0.2*tanh(W_hh r_t + b_hh + W_in x_t + b_in)
// 256 blocks x 512 threads, cooperative. Block = (batch b = blk&127, row-half = blk>>7).
// All weights live in VGPRs as packed f16; per-step pair exchange of 256 f16 r-values
// through d_ws using agent-scope atomics (flags = per-wave release counters).

typedef _Float16 half2v __attribute__((ext_vector_type(2)));

__device__ __forceinline__ float dot2f(uint32_t a, uint32_t b, float c) {
#if __has_builtin(__builtin_amdgcn_fdot2)
  return __builtin_amdgcn_fdot2(__builtin_bit_cast(half2v, a),
                                __builtin_bit_cast(half2v, b), c, false);
#else
  half2v ha = __builtin_bit_cast(half2v, a), hb = __builtin_bit_cast(half2v, b);
  return c + (float)ha[0] * (float)hb[0] + (float)ha[1] * (float)hb[1];
#endif
}
__device__ __forceinline__ uint32_t pk_rtz(float a, float b) {
  return __builtin_bit_cast(uint32_t, __builtin_amdgcn_cvt_pkrtz(a, b));
}
__device__ __forceinline__ uint32_t pk_rn(float a, float b) {
  unsigned lo = __half_as_ushort(__float2half(a));
  unsigned hi = __half_as_ushort(__float2half(b));
  return lo | (hi << 16);
}
__device__ __forceinline__ float fast_tanh(float x) {
  float e = __expf(2.0f * x);
  return 1.0f - 2.0f * __builtin_amdgcn_rcpf(e + 1.0f);
}

#define NSTEP 1000

__global__ __launch_bounds__(512, 2) void rnn_step_kernel(
    const float* __restrict__ x,   const float* __restrict__ Win,
    const float* __restrict__ bin, const float* __restrict__ Whh,
    const float* __restrict__ bhh, const float* __restrict__ Wout,
    const float* __restrict__ bout, float* __restrict__ out,
    uint32_t* __restrict__ ws)
{
  const int tid  = threadIdx.x;
  const int blk  = blockIdx.x;
  const int b    = blk & 127;
  const int half = blk >> 7;     // which 256-row half this block produces
  const int kg   = tid & 7;      // k-group: 32 own k's + 32 partner k's
  const int rg   = tid >> 3;     // row-group: 4 consecutive rows
  const int lane = tid & 63;
  const int h0   = half * 256 + rg * 4;

  // d_ws layout: flags 256*16 u32 (64B spacing) | slots 256 * (2 parities * 128 u32)
  uint32_t* flagOwn = ws + blk * 16;
  uint32_t* flagPar = ws + (blk ^ 128) * 16;
  uint32_t* slotOwn = ws + 4096 + blk * 256;
  uint32_t* slotPar = ws + 4096 + (blk ^ 128) * 256;

  // r state as packed f16 pairs; 16 chunks of 20 u32 (64B data + 16B pad -> bank-exact)
  __shared__ uint32_t rbuf[2][320];

  uint32_t wO[4][16], wP[4][16], wI[4][4];
  float bias[4], woutR[4], rOld[4];
  const int coK = half * 256 + kg * 32;
  const int cpK = 256 - half * 256 + kg * 32;
#pragma unroll
  for (int r = 0; r < 4; r++) {
    const float* row = Whh + (long)(h0 + r) * 512;
#pragma unroll
    for (int j = 0; j < 16; j++) {
      wO[r][j] = pk_rn(row[coK + 2 * j], row[coK + 2 * j + 1]);
      wP[r][j] = pk_rn(row[cpK + 2 * j], row[cpK + 2 * j + 1]);
    }
    const float* irow = Win + (h0 + r) * 64;
#pragma unroll
    for (int j = 0; j < 4; j++)
      wI[r][j] = pk_rn(irow[kg * 8 + 2 * j], irow[kg * 8 + 2 * j + 1]);
    bias[r]  = bhh[h0 + r] + bin[h0 + r];
    woutR[r] = Wout[h0 + r];
    rOld[r]  = 0.0f;
  }
  const float bOut = bout[0];

  for (int i = tid; i < 640; i += 512) ((uint32_t*)rbuf)[i] = 0;
  __syncthreads();

  const float* xptr = x + (long)b * 64000 + kg * 8;
  float* outR = out + 128000 + (long)b * 512 + h0;
  float* dvP  = out + b;

  unsigned fpre = 0;
  int cur = 0;

  for (int t = 0; t < NSTEP; ++t) {
    const unsigned need = 8u * (unsigned)t;
    const bool hasPart  = (t > 0);
    const bool ready    = hasPart && (fpre >= need);
    const int par = t & 1;
    uint32_t rp[16];

    // Partner r (fast path): counter already satisfied at prefetch time -> issue
    // loads now; latency hides under the own-half dot phase below.
    if (ready) {
      const unsigned long long* sp =
          (const unsigned long long*)(slotPar + par * 128) + kg * 8;
#pragma unroll
      for (int j = 0; j < 8; j++) {
        unsigned long long v =
            __hip_atomic_load(sp + j, __ATOMIC_RELAXED, __HIP_MEMORY_SCOPE_AGENT);
        rp[2 * j]     = (uint32_t)v;
        rp[2 * j + 1] = (uint32_t)(v >> 32);
      }
    }

    // x_t chunk (8 f32) -> f16 pairs
    const float4 xa = *(const float4*)(xptr + t * 64);
    const float4 xb = *(const float4*)(xptr + t * 64 + 4);
    uint32_t xp[4] = { pk_rtz(xa.x, xa.y), pk_rtz(xa.z, xa.w),
                       pk_rtz(xb.x, xb.y), pk_rtz(xb.z, xb.w) };

    // A-phase: own-half k's from LDS (conflict-free 80B-strided chunks)
    const uint4* rc = (const uint4*)&rbuf[cur][(half * 8 + kg) * 20];
    const uint4 q0 = rc[0], q1 = rc[1], q2 = rc[2], q3 = rc[3];
    const uint32_t ro[16] = { q0.x, q0.y, q0.z, q0.w, q1.x, q1.y, q1.z, q1.w,
                              q2.x, q2.y, q2.z, q2.w, q3.x, q3.y, q3.z, q3.w };
    float acc[4];
#pragma unroll
    for (int r = 0; r < 4; r++) {
      float a = 0.0f;
#pragma unroll
      for (int j = 0; j < 16; j++) a = dot2f(wO[r][j], ro[j], a);
#pragma unroll
      for (int j = 0; j < 4; j++)  a = dot2f(wI[r][j], xp[j], a);
      acc[r] = a;
    }

    // Partner r (slow path / t==0)
    if (hasPart && !ready) {
      unsigned f = fpre;
      while (f < need) {
        __builtin_amdgcn_s_sleep(2);
        f = __hip_atomic_load(flagPar, __ATOMIC_RELAXED, __HIP_MEMORY_SCOPE_AGENT);
      }
      const unsigned long long* sp =
          (const unsigned long long*)(slotPar + par * 128) + kg * 8;
#pragma unroll
      for (int j = 0; j < 8; j++) {
        unsigned long long v =
            __hip_atomic_load(sp + j, __ATOMIC_RELAXED, __HIP_MEMORY_SCOPE_AGENT);
        rp[2 * j]     = (uint32_t)v;
        rp[2 * j + 1] = (uint32_t)(v >> 32);
      }
    } else if (!hasPart) {
#pragma unroll
      for (int j = 0; j < 16; j++) rp[j] = 0;
    }

    // B-phase: partner-half k's + reduce over the 8 k-groups (lane bits 0..2)
#pragma unroll
    for (int r = 0; r < 4; r++) {
      float a = acc[r];
#pragma unroll
      for (int j = 0; j < 16; j++) a = dot2f(wP[r][j], rp[j], a);
      a += __shfl_xor(a, 1);
      a += __shfl_xor(a, 2);
      a += __shfl_xor(a, 4);
      acc[r] = a;
    }

    float rnew[4], p = 0.0f;
#pragma unroll
    for (int r = 0; r < 4; r++) {
      float th = fast_tanh(acc[r] + bias[r]);
      rnew[r] = 0.8f * rOld[r] + 0.2f * th;
      rOld[r] = rnew[r];
      p += woutR[r] * rnew[r];
    }

    const int nxt = cur ^ 1;
    const uint32_t p01 = pk_rn(rnew[0], rnew[1]);
    const uint32_t p23 = pk_rn(rnew[2], rnew[3]);
    if (kg == 0) {
      uint32_t* wd = &rbuf[nxt][(half * 8 + (rg >> 3)) * 20 + (rg & 7) * 2];
      wd[0] = p01;
      wd[1] = p23;
      unsigned long long v = ((unsigned long long)p23 << 32) | p01;
      __hip_atomic_store((unsigned long long*)(slotOwn + (par ^ 1) * 128) + rg, v,
                         __ATOMIC_RELAXED, __HIP_MEMORY_SCOPE_AGENT);
    }
    // per-wave release: publishes this wave's slot piece (counter -> 8*(t+1))
    if (lane == 0)
      __hip_atomic_fetch_add(flagOwn, 1u, __ATOMIC_RELEASE, __HIP_MEMORY_SCOPE_AGENT);

    // hidden-state output (after the release so its HBM ack isn't waited on)
    if (kg == 0)
      *(float4*)(outR + (long)t * 65536) =
          make_float4(rnew[0], rnew[1], rnew[2], rnew[3]);

    // decision variable: reduce over row-groups (lane bits 3..5), one atomic/wave
    p += __shfl_xor(p, 8);
    p += __shfl_xor(p, 16);
    p += __shfl_xor(p, 32);
    if (lane == 0) {
      if (half == 0 && tid == 0) p += bOut;
      unsafeAtomicAdd(dvP + t * 128, p);
    }

    // prefetch partner counter for next step
    fpre = __hip_atomic_load(flagPar, __ATOMIC_RELAXED, __HIP_MEMORY_SCOPE_AGENT);
    __syncthreads();
    cur = nxt;
  }
}

extern "C" void kernel_launch(void* const* d_in, const int* in_sizes, int n_in,
                              void* d_out, int out_size, void* d_ws, size_t ws_size,
                              hipStream_t stream) {
  const float* x    = (const float*)d_in[0];
  const float* Win  = (const float*)d_in[1];
  const float* bin  = (const float*)d_in[2];
  const float* Whh  = (const float*)d_in[3];
  const float* bhh  = (const float*)d_in[4];
  const float* Wout = (const float*)d_in[5];
  const float* bout = (const float*)d_in[6];
  float* out   = (float*)d_out;
  uint32_t* ws = (uint32_t*)d_ws;

  // decision accumulator and exchange flags must start at zero every launch
  hipMemsetAsync(d_out, 0, 128000 * sizeof(float), stream);
  hipMemsetAsync(d_ws, 0, 4096 * sizeof(uint32_t), stream);

  void* args[] = {&x, &Win, &bin, &Whh, &bhh, &Wout, &bout, &out, &ws};
  hipError_t e = hipLaunchCooperativeKernel((void*)rnn_step_kernel, dim3(256),
                                            dim3(512), args, 0, stream);
  if (e != hipSuccess) {
    // plain launch fallback: 256 blocks at 1 block/CU are de-facto co-resident
    rnn_step_kernel<<<dim3(256), dim3(512), 0, stream>>>(x, Win, bin, Whh, bhh,
                                                         Wout, bout, out, ws);
  }
}

// Round 3
// 3481.260 us; speedup vs baseline: 5.8863x; 5.8863x over previous
//
#include <hip/hip_runtime.h>
#include <hip/hip_fp16.h>
#include <stdint.h>

// DMSRNN: r_{t+1} = 0.8*r_t + 0.2*tanh(W_hh r_t + b_hh + W_in x_t + b_in)
// 256 blocks x 512 threads, cooperative. Block = (batch b = blk&127, row-half = blk>>7).
// All weights live in VGPRs as packed f16; per-step pair exchange of 256 f16 r-values
// through d_ws using RELAXED agent-scope atomics (sc1, no L2 cache-maintenance ops).
// Hand-rolled release: s_waitcnt vmcnt(0) after sc1 slot stores -> relaxed flag add.
// (Compiler RELEASE at agent scope emits buffer_wbl2 = full L2 writeback per step,
//  which was the 20 us/step stall in round 1.)

typedef _Float16 half2v __attribute__((ext_vector_type(2)));

__device__ __forceinline__ float dot2f(uint32_t a, uint32_t b, float c) {
#if __has_builtin(__builtin_amdgcn_fdot2)
  return __builtin_amdgcn_fdot2(__builtin_bit_cast(half2v, a),
                                __builtin_bit_cast(half2v, b), c, false);
#else
  half2v ha = __builtin_bit_cast(half2v, a), hb = __builtin_bit_cast(half2v, b);
  return c + (float)ha[0] * (float)hb[0] + (float)ha[1] * (float)hb[1];
#endif
}
__device__ __forceinline__ uint32_t pk_rtz(float a, float b) {
  return __builtin_bit_cast(uint32_t, __builtin_amdgcn_cvt_pkrtz(a, b));
}
__device__ __forceinline__ uint32_t pk_rn(float a, float b) {
  unsigned lo = __half_as_ushort(__float2half(a));
  unsigned hi = __half_as_ushort(__float2half(b));
  return lo | (hi << 16);
}
__device__ __forceinline__ float fast_tanh(float x) {
  float e = __expf(2.0f * x);
  return 1.0f - 2.0f * __builtin_amdgcn_rcpf(e + 1.0f);
}

#define NSTEP 1000

__global__ __launch_bounds__(512, 2) void rnn_step_kernel(
    const float* __restrict__ x,   const float* __restrict__ Win,
    const float* __restrict__ bin, const float* __restrict__ Whh,
    const float* __restrict__ bhh, const float* __restrict__ Wout,
    const float* __restrict__ bout, float* __restrict__ out,
    uint32_t* __restrict__ ws)
{
  const int tid  = threadIdx.x;
  const int blk  = blockIdx.x;
  const int b    = blk & 127;
  const int half = blk >> 7;     // which 256-row half this block produces
  const int kg   = tid & 7;      // k-group: 32 own k's + 32 partner k's
  const int rg   = tid >> 3;     // row-group: 4 consecutive rows
  const int lane = tid & 63;
  const int h0   = half * 256 + rg * 4;

  // d_ws layout: flags 256*16 u32 (64B spacing) | slots 256 * (2 parities * 128 u32)
  uint32_t* flagOwn = ws + blk * 16;
  uint32_t* flagPar = ws + (blk ^ 128) * 16;
  uint32_t* slotOwn = ws + 4096 + blk * 256;
  uint32_t* slotPar = ws + 4096 + (blk ^ 128) * 256;

  // r state as packed f16 pairs; 16 chunks of 20 u32 (64B data + 16B pad -> bank-exact)
  __shared__ uint32_t rbuf[2][320];

  uint32_t wO[4][16], wP[4][16], wI[4][4];
  float bias[4], woutR[4], rOld[4];
  const int coK = half * 256 + kg * 32;
  const int cpK = 256 - half * 256 + kg * 32;
#pragma unroll
  for (int r = 0; r < 4; r++) {
    const float* row = Whh + (long)(h0 + r) * 512;
#pragma unroll
    for (int j = 0; j < 16; j++) {
      wO[r][j] = pk_rn(row[coK + 2 * j], row[coK + 2 * j + 1]);
      wP[r][j] = pk_rn(row[cpK + 2 * j], row[cpK + 2 * j + 1]);
    }
    const float* irow = Win + (h0 + r) * 64;
#pragma unroll
    for (int j = 0; j < 4; j++)
      wI[r][j] = pk_rn(irow[kg * 8 + 2 * j], irow[kg * 8 + 2 * j + 1]);
    bias[r]  = bhh[h0 + r] + bin[h0 + r];
    woutR[r] = Wout[h0 + r];
    rOld[r]  = 0.0f;
  }
  const float bOut = bout[0];

  for (int i = tid; i < 640; i += 512) ((uint32_t*)rbuf)[i] = 0;
  __syncthreads();

  const float* xptr = x + (long)b * 64000 + kg * 8;
  float* outR = out + 128000 + (long)b * 512 + h0;
  float* dvP  = out + b;

  unsigned fpre = 0;
  int cur = 0;

  for (int t = 0; t < NSTEP; ++t) {
    const unsigned need = 8u * (unsigned)t;
    const bool hasPart  = (t > 0);
    const bool ready    = hasPart && (fpre >= need);
    const int par = t & 1;
    uint32_t rp[16];

    // Partner r (fast path): counter already satisfied at prefetch time -> issue
    // loads now; latency hides under the own-half dot phase below.
    if (ready) {
      const unsigned long long* sp =
          (const unsigned long long*)(slotPar + par * 128) + kg * 8;
#pragma unroll
      for (int j = 0; j < 8; j++) {
        unsigned long long v =
            __hip_atomic_load(sp + j, __ATOMIC_RELAXED, __HIP_MEMORY_SCOPE_AGENT);
        rp[2 * j]     = (uint32_t)v;
        rp[2 * j + 1] = (uint32_t)(v >> 32);
      }
    }

    // x_t chunk (8 f32) -> f16 pairs
    const float4 xa = *(const float4*)(xptr + t * 64);
    const float4 xb = *(const float4*)(xptr + t * 64 + 4);
    uint32_t xp[4] = { pk_rtz(xa.x, xa.y), pk_rtz(xa.z, xa.w),
                       pk_rtz(xb.x, xb.y), pk_rtz(xb.z, xb.w) };

    // A-phase: own-half k's from LDS (conflict-free 80B-strided chunks)
    const uint4* rc = (const uint4*)&rbuf[cur][(half * 8 + kg) * 20];
    const uint4 q0 = rc[0], q1 = rc[1], q2 = rc[2], q3 = rc[3];
    const uint32_t ro[16] = { q0.x, q0.y, q0.z, q0.w, q1.x, q1.y, q1.z, q1.w,
                              q2.x, q2.y, q2.z, q2.w, q3.x, q3.y, q3.z, q3.w };
    float acc[4];
#pragma unroll
    for (int r = 0; r < 4; r++) {
      float a = 0.0f;
#pragma unroll
      for (int j = 0; j < 16; j++) a = dot2f(wO[r][j], ro[j], a);
#pragma unroll
      for (int j = 0; j < 4; j++)  a = dot2f(wI[r][j], xp[j], a);
      acc[r] = a;
    }

    // Partner r (slow path / t==0)
    if (hasPart && !ready) {
      unsigned f = fpre;
      while (f < need) {
        __builtin_amdgcn_s_sleep(1);
        f = __hip_atomic_load(flagPar, __ATOMIC_RELAXED, __HIP_MEMORY_SCOPE_AGENT);
      }
      const unsigned long long* sp =
          (const unsigned long long*)(slotPar + par * 128) + kg * 8;
#pragma unroll
      for (int j = 0; j < 8; j++) {
        unsigned long long v =
            __hip_atomic_load(sp + j, __ATOMIC_RELAXED, __HIP_MEMORY_SCOPE_AGENT);
        rp[2 * j]     = (uint32_t)v;
        rp[2 * j + 1] = (uint32_t)(v >> 32);
      }
    } else if (!hasPart) {
#pragma unroll
      for (int j = 0; j < 16; j++) rp[j] = 0;
    }

    // B-phase: partner-half k's + reduce over the 8 k-groups (lane bits 0..2)
#pragma unroll
    for (int r = 0; r < 4; r++) {
      float a = acc[r];
#pragma unroll
      for (int j = 0; j < 16; j++) a = dot2f(wP[r][j], rp[j], a);
      a += __shfl_xor(a, 1);
      a += __shfl_xor(a, 2);
      a += __shfl_xor(a, 4);
      acc[r] = a;
    }

    float rnew[4], p = 0.0f;
#pragma unroll
    for (int r = 0; r < 4; r++) {
      float th = fast_tanh(acc[r] + bias[r]);
      rnew[r] = 0.8f * rOld[r] + 0.2f * th;
      rOld[r] = rnew[r];
      p += woutR[r] * rnew[r];
    }

    const int nxt = cur ^ 1;
    const uint32_t p01 = pk_rn(rnew[0], rnew[1]);
    const uint32_t p23 = pk_rn(rnew[2], rnew[3]);
    if (kg == 0) {
      uint32_t* wd = &rbuf[nxt][(half * 8 + (rg >> 3)) * 20 + (rg & 7) * 2];
      wd[0] = p01;
      wd[1] = p23;
      unsigned long long v = ((unsigned long long)p23 << 32) | p01;
      __hip_atomic_store((unsigned long long*)(slotOwn + (par ^ 1) * 128) + rg, v,
                         __ATOMIC_RELAXED, __HIP_MEMORY_SCOPE_AGENT);
    }

    // Hand-rolled release: sc1 slot stores are ack'd from the coherence point,
    // so vmcnt(0) == globally visible. Then a RELAXED flag add (no buffer_wbl2).
    asm volatile("s_waitcnt vmcnt(0)" ::: "memory");
    if (lane == 0)
      __hip_atomic_fetch_add(flagOwn, 1u, __ATOMIC_RELAXED, __HIP_MEMORY_SCOPE_AGENT);

    // hidden-state output (after the release so its HBM ack isn't waited on)
    if (kg == 0)
      *(float4*)(outR + (long)t * 65536) =
          make_float4(rnew[0], rnew[1], rnew[2], rnew[3]);

    // decision variable: reduce over row-groups (lane bits 3..5), one atomic/wave
    p += __shfl_xor(p, 8);
    p += __shfl_xor(p, 16);
    p += __shfl_xor(p, 32);
    if (lane == 0) {
      if (half == 0 && tid == 0) p += bOut;
      unsafeAtomicAdd(dvP + t * 128, p);
    }

    // prefetch partner counter for next step
    fpre = __hip_atomic_load(flagPar, __ATOMIC_RELAXED, __HIP_MEMORY_SCOPE_AGENT);
    __syncthreads();
    cur = nxt;
  }
}

extern "C" void kernel_launch(void* const* d_in, const int* in_sizes, int n_in,
                              void* d_out, int out_size, void* d_ws, size_t ws_size,
                              hipStream_t stream) {
  const float* x    = (const float*)d_in[0];
  const float* Win  = (const float*)d_in[1];
  const float* bin  = (const float*)d_in[2];
  const float* Whh  = (const float*)d_in[3];
  const float* bhh  = (const float*)d_in[4];
  const float* Wout = (const float*)d_in[5];
  const float* bout = (const float*)d_in[6];
  float* out   = (float*)d_out;
  uint32_t* ws = (uint32_t*)d_ws;

  // decision accumulator and exchange flags must start at zero every launch
  hipMemsetAsync(d_out, 0, 128000 * sizeof(float), stream);
  hipMemsetAsync(d_ws, 0, 4096 * sizeof(uint32_t), stream);

  void* args[] = {&x, &Win, &bin, &Whh, &bhh, &Wout, &bout, &out, &ws};
  hipError_t e = hipLaunchCooperativeKernel((void*)rnn_step_kernel, dim3(256),
                                            dim3(512), args, 0, stream);
  if (e != hipSuccess) {
    // plain launch fallback: 256 blocks at 1 block/CU are de-facto co-resident
    rnn_step_kernel<<<dim3(256), dim3(512), 0, stream>>>(x, Win, bin, Whh, bhh,
                                                         Wout, bout, out, ws);
  }
}